// Round 6
// baseline (263.301 us; speedup 1.0000x reference)
//
#include <hip/hip_runtime.h>
#include <hip/hip_bf16.h>
#include <math.h>

#define N_NODES 20000
#define N_EDGES 320000
#define F_IN 22
#define H_HEADS 4
#define C_DIM 64
#define HC 256
#define G_GRAPHS 20
#define OUT_DIM 128
#define NODES_PER_G 1000
#define POOL_CHUNKS 8
#define NODES_PER_CHUNK (NODES_PER_G / POOL_CHUNKS)
#define ELL_CAP 64          // slots per node; deg capped at 63 (Poisson(16) max ~45)
#define SCAT_NB ((N_EDGES + 255) / 256)   // 1250
#define INPROJ_NB (N_NODES / 4)           // 5000
#define GAT_NB (N_NODES / 4)              // 5000 blocks; 5000 = 8 * 625
#define GAT_CPX (GAT_NB / 8)              // 625 blocks per XCD

#if __has_builtin(__builtin_amdgcn_exp2f)
#define EXP2F __builtin_amdgcn_exp2f
#else
#define EXP2F exp2f
#endif

typedef unsigned short ushortT;
typedef __attribute__((ext_vector_type(8))) short short8;
typedef __attribute__((ext_vector_type(4))) float v4f;
typedef __attribute__((ext_vector_type(2))) float f2;

typedef const __attribute__((address_space(1))) void* gas_p;
typedef __attribute__((address_space(3))) void* las_p;

__device__ inline ushortT f2bf(float f) {
    unsigned int u = __float_as_uint(f);
    unsigned int r = (u + 0x7fffu + ((u >> 16) & 1u)) >> 16;   // RNE
    return (ushortT)r;
}

// ---------------- fused front: ELL scatter + input projection + weight conv ----
__global__ __launch_bounds__(256) void front_kernel(
        const int* __restrict__ esrc, const int* __restrict__ edst,
        int* __restrict__ fill, int* __restrict__ ell,
        const float* __restrict__ x, const float* __restrict__ Win,
        const float* __restrict__ bin, ushortT* __restrict__ h0b,
        const float* __restrict__ Wl0, const float* __restrict__ Wr0,
        const float* __restrict__ Wl1, const float* __restrict__ Wr1,
        const float* __restrict__ Wl2, const float* __restrict__ Wr2,
        ushortT* __restrict__ Bt0, ushortT* __restrict__ Bt1, ushortT* __restrict__ Bt2) {
    int tid = threadIdx.x;
    if (blockIdx.x < SCAT_NB) {
        int i = blockIdx.x * 256 + tid;
        if (i < N_EDGES) {
            int d = edst[i];
            int p = atomicAdd(&fill[d], 1);
            if (p < ELL_CAP) ell[(d << 6) + p] = esrc[i];
        }
        return;
    }
    if (blockIdx.x < SCAT_NB + INPROJ_NB) {
        int node = (blockIdx.x - SCAT_NB) * 4 + (tid >> 6);
        int c = tid & 63;
        float acc = bin[c];
        const float* xr = x + node * F_IN;
#pragma unroll
        for (int f = 0; f < F_IN; f++) acc += xr[f] * Win[f * C_DIM + c];
        h0b[node * C_DIM + c] = f2bf(acc > 0.f ? acc : 0.f);
        return;
    }
    int flat = blockIdx.x - SCAT_NB - INPROJ_NB;
    int z = flat >> 6;               // 0..5
    int rem = flat & 63;
    int kx = (rem >> 3) * 32;
    int nx = (rem & 7) * 32;
    int layer = z >> 1, isR = z & 1;
    const float* src; ushortT* dst; int K;
    if (layer == 0)      { K = 64;  dst = Bt0; src = isR ? Wr0 : Wl0; }
    else if (layer == 1) { K = 256; dst = Bt1; src = isR ? Wr1 : Wl1; }
    else                 { K = 256; dst = Bt2; src = isR ? Wr2 : Wl2; }
    if (kx >= K) return;
    __shared__ float tile[32][33];
    int c = tid & 31, r8 = tid >> 5;
#pragma unroll
    for (int i = 0; i < 4; i++) {
        int kk = r8 + i * 8;
        tile[kk][c] = src[(kx + kk) * 256 + nx + c];
    }
    __syncthreads();
    int nbase = isR ? 256 : 0;
#pragma unroll
    for (int i = 0; i < 4; i++) {
        int nn = r8 + i * 8;
        dst[(size_t)(nbase + nx + nn) * K + kx + c] = f2bf(tile[c][nn]);
    }
}

// ---------------- bf16 MFMA dual GEMM (global_load_lds staging, m97-style) ------
#define GBM 128
#define GBN 128
#define GBK 32

__global__ __launch_bounds__(256) void gemm_mfma_kernel(
        const ushortT* __restrict__ A, const ushortT* __restrict__ Bt,
        ushortT* __restrict__ XLb, ushortT* __restrict__ XRb, int M, int K) {
    __shared__ ushortT As[GBM * GBK];   // unpadded: glds needs base + lane*16B contiguity
    __shared__ ushortT Bs[GBN * GBK];
    int tid = threadIdx.x;
    int wave = tid >> 6, lane = tid & 63;
    int wm = wave & 1, wn = wave >> 1;
    int bm0 = blockIdx.y * GBM;
    int bn0 = blockIdx.x * GBN;

    v4f acc[4][4];
#pragma unroll
    for (int mt = 0; mt < 4; mt++)
#pragma unroll
        for (int nt = 0; nt < 4; nt++) acc[mt][nt] = (v4f){0.f, 0.f, 0.f, 0.f};

    // staging: each wave fills two 16-row strips (1024 B each) of As and Bs.
    // lane l covers row strip_base + l/4, element col (l&3)*8  (= lane*16 B).
    int srow = lane >> 2;
    int scol = (lane & 3) * 8;
    int arow0 = wave * 16 + srow;       // strip 0 row
    int arow1 = arow0 + 64;             // strip 1 row
    int ag0 = bm0 + arow0; if (ag0 >= M) ag0 = 0;
    int ag1 = bm0 + arow1; if (ag1 >= M) ag1 = 0;
    const ushortT* aptr0 = A + (size_t)ag0 * K + scol;
    const ushortT* aptr1 = A + (size_t)ag1 * K + scol;
    const ushortT* bptr0 = Bt + (size_t)(bn0 + arow0) * K + scol;
    const ushortT* bptr1 = Bt + (size_t)(bn0 + arow1) * K + scol;
    las_p lA0 = (las_p)&As[(wave * 16) * GBK];
    las_p lA1 = (las_p)&As[(wave * 16 + 64) * GBK];
    las_p lB0 = (las_p)&Bs[(wave * 16) * GBK];
    las_p lB1 = (las_p)&Bs[(wave * 16 + 64) * GBK];

    int mrow = lane & 15;
    int koff = (lane >> 4) * 8;

    for (int k0 = 0; k0 < K; k0 += GBK) {
        __builtin_amdgcn_global_load_lds((gas_p)(aptr0 + k0), lA0, 16, 0, 0);
        __builtin_amdgcn_global_load_lds((gas_p)(aptr1 + k0), lA1, 16, 0, 0);
        __builtin_amdgcn_global_load_lds((gas_p)(bptr0 + k0), lB0, 16, 0, 0);
        __builtin_amdgcn_global_load_lds((gas_p)(bptr1 + k0), lB1, 16, 0, 0);
        __syncthreads();
        short8 af[4], bf[4];
#pragma unroll
        for (int mt = 0; mt < 4; mt++)
            af[mt] = *(const short8*)&As[(wm * 64 + mt * 16 + mrow) * GBK + koff];
#pragma unroll
        for (int nt = 0; nt < 4; nt++)
            bf[nt] = *(const short8*)&Bs[(wn * 64 + nt * 16 + mrow) * GBK + koff];
#pragma unroll
        for (int mt = 0; mt < 4; mt++)
#pragma unroll
            for (int nt = 0; nt < 4; nt++)
                acc[mt][nt] = __builtin_amdgcn_mfma_f32_16x16x32_bf16(af[mt], bf[nt], acc[mt][nt], 0, 0, 0);
        __syncthreads();
    }

    int cbase = bn0 + wn * 64;
    ushortT* dst = XLb;
    if (cbase >= 256) { dst = XRb; cbase -= 256; }
    int col = cbase + (lane & 15);
    int rbase = bm0 + wm * 64 + ((lane >> 4) * 4);
#pragma unroll
    for (int mt = 0; mt < 4; mt++) {
#pragma unroll
        for (int reg = 0; reg < 4; reg++) {
            int row = rbase + mt * 16 + reg;
            if (row < M) {
#pragma unroll
                for (int nt = 0; nt < 4; nt++)
                    dst[(size_t)row * 256 + col + nt * 16] = f2bf(acc[mt][nt][reg]);
            }
        }
    }
}

// ---------------- GATv2 layer ----------------
// One wave per node; TWO edges per wave: lanes 0-31 process even edge slots,
// lanes 32-63 odd slots. Each lane holds 8 channels (16 B uint4 gather).
// Head = 8 lanes -> butterfly is 3 ds_swizzle steps SHARED by both edges
// (vs 4 per edge before); 1 VMEM instr per 2 edges (vs 2); exp/den/min 1 per 2.
// R2 proved gather latency is TLP-hidden -> the lever is instrs/edge.
template <int PAT>
__device__ inline float swz_add(float p) {
    return p + __int_as_float(__builtin_amdgcn_ds_swizzle(__float_as_int(p), PAT));
}

__device__ inline void gat_edge2(uint4 curu,
        f2 xr01, f2 xr23, f2 xr45, f2 xr67,
        f2 a01, f2 a23, f2 a45, f2 a67,
        float live, float& den,
        f2& acc01, f2& acc23, f2& acc45, f2& acc67) {
    f2 x01, x23, x45, x67;
    x01.x = __uint_as_float(curu.x << 16);
    x01.y = __uint_as_float(curu.x & 0xffff0000u);
    x23.x = __uint_as_float(curu.y << 16);
    x23.y = __uint_as_float(curu.y & 0xffff0000u);
    x45.x = __uint_as_float(curu.z << 16);
    x45.y = __uint_as_float(curu.z & 0xffff0000u);
    x67.x = __uint_as_float(curu.w << 16);
    x67.y = __uint_as_float(curu.w & 0xffff0000u);
    f2 t01 = x01 + xr01;
    f2 t23 = x23 + xr23;
    f2 t45 = x45 + xr45;
    f2 t67 = x67 + xr67;
    t01 = __builtin_elementwise_max(t01, t01 * 0.2f);   // leaky_relu(0.2)
    t23 = __builtin_elementwise_max(t23, t23 * 0.2f);
    t45 = __builtin_elementwise_max(t45, t45 * 0.2f);
    t67 = __builtin_elementwise_max(t67, t67 * 0.2f);
    f2 pp = t01 * a01;
    pp = __builtin_elementwise_fma(t23, a23, pp);
    pp = __builtin_elementwise_fma(t45, a45, pp);
    pp = __builtin_elementwise_fma(t67, a67, pp);
    float p = pp.x + pp.y;
    p = swz_add<0x041F>(p);        // xor 1   (8-lane head group reduce,
    p = swz_add<0x081F>(p);        // xor 2    both edges simultaneously)
    p = swz_add<0x101F>(p);        // xor 4
    p = fminf(p, 110.f);           // log2-domain safety clamp
    float w = EXP2F(p) * live;     // att pre-scaled by log2(e); live=0 on phantom
    den += w;
    f2 wv = {w, w};
    acc01 = __builtin_elementwise_fma(wv, x01, acc01);
    acc23 = __builtin_elementwise_fma(wv, x23, acc23);
    acc45 = __builtin_elementwise_fma(wv, x45, acc45);
    acc67 = __builtin_elementwise_fma(wv, x67, acc67);
}

__global__ __launch_bounds__(256) void gat_layer_kernel(
        const ushortT* __restrict__ xlb, const ushortT* __restrict__ xrb,
        const int* __restrict__ ell, const int* __restrict__ fill,
        const float* __restrict__ att, const float* __restrict__ bias,
        const float* __restrict__ hprev,
        float* __restrict__ hout, ushortT* __restrict__ houtb) {
    int lane = threadIdx.x & 63;
    int q = lane & 31;          // channel octet: chans 8q..8q+7; head = q>>3
    int half = lane >> 5;       // 0: even slots, 1: odd slots
    // XCD-affinity swizzle (kept from R5, bijective: 5000 = 8 * 625)
    int bid = blockIdx.x;
    int lb = (bid & 7) * GAT_CPX + (bid >> 3);
    int d = lb * 4 + (threadIdx.x >> 6);

    const uint4* xl4 = (const uint4*)xlb;
    uint4 xru = ((const uint4*)xrb)[d * 32 + q];
    f2 xr01, xr23, xr45, xr67;
    xr01.x = __uint_as_float(xru.x << 16);
    xr01.y = __uint_as_float(xru.x & 0xffff0000u);
    xr23.x = __uint_as_float(xru.y << 16);
    xr23.y = __uint_as_float(xru.y & 0xffff0000u);
    xr45.x = __uint_as_float(xru.z << 16);
    xr45.y = __uint_as_float(xru.z & 0xffff0000u);
    xr67.x = __uint_as_float(xru.w << 16);
    xr67.y = __uint_as_float(xru.w & 0xffff0000u);

    const float4* att4 = (const float4*)att;
    float4 av0 = att4[q * 2];
    float4 av1 = att4[q * 2 + 1];
    const float LOG2E = 1.44269504088896f;
    f2 a01 = {av0.x * LOG2E, av0.y * LOG2E};
    f2 a23 = {av0.z * LOG2E, av0.w * LOG2E};
    f2 a45 = {av1.x * LOG2E, av1.y * LOG2E};
    f2 a67 = {av1.z * LOG2E, av1.w * LOG2E};

    int deg = fill[d];
    if (deg > ELL_CAP - 1) deg = ELL_CAP - 1;   // never triggers for this input
    int M = deg + 1;                             // + self-loop at edge index deg

    int idx = (lane < deg) ? ell[(d << 6) + lane] : d;

    float den = 0.f;
    f2 acc01 = {0.f, 0.f}, acc23 = {0.f, 0.f}, acc45 = {0.f, 0.f}, acc67 = {0.f, 0.f};

    // prefetch 2 pairs (4 slots), straight-line body (R3 lesson: no branches)
    uint4 buf[2];
#pragma unroll
    for (int k = 0; k < 2; k++) {
        int sA = __builtin_amdgcn_readlane(idx, 2 * k);
        int sB = __builtin_amdgcn_readlane(idx, 2 * k + 1);
        int ni = half ? sB : sA;
        buf[k] = xl4[(size_t)ni * 32 + q];
    }
    int P2 = (M + 1) >> 1;           // edge pairs
    int G = (P2 + 1) >> 1;           // groups of 2 pairs = 4 slots (same pad as R0)
    for (int g = 0; g < G; g++) {
#pragma unroll
        for (int k = 0; k < 2; k++) {
            uint4 cur = buf[k];
            int np = 2 * g + 2 + k;                       // prefetch pair (dist 2)
            int sA = __builtin_amdgcn_readlane(idx, (2 * np) & 63);      // junk ok
            int sB = __builtin_amdgcn_readlane(idx, (2 * np + 1) & 63);
            int ni = half ? sB : sA;
            buf[k] = xl4[(size_t)ni * 32 + q];
            int slot = (2 * g + k) * 2 + half;
            float live = (slot < M) ? 1.0f : 0.0f;
            gat_edge2(cur, xr01, xr23, xr45, xr67, a01, a23, a45, a67,
                      live, den, acc01, acc23, acc45, acc67);
        }
    }

    // combine even-slot (lanes 0-31) and odd-slot (32-63) partials
    den     += __shfl_xor(den, 32);
    acc01.x += __shfl_xor(acc01.x, 32);
    acc01.y += __shfl_xor(acc01.y, 32);
    acc23.x += __shfl_xor(acc23.x, 32);
    acc23.y += __shfl_xor(acc23.y, 32);
    acc45.x += __shfl_xor(acc45.x, 32);
    acc45.y += __shfl_xor(acc45.y, 32);
    acc67.x += __shfl_xor(acc67.x, 32);
    acc67.y += __shfl_xor(acc67.y, 32);

    float inv = 1.f / (den + 1e-16f);
    float4 bv0 = ((const float4*)bias)[q * 2];
    float4 bv1 = ((const float4*)bias)[q * 2 + 1];
    float v0 = acc01.x * inv + bv0.x;
    float v1 = acc01.y * inv + bv0.y;
    float v2 = acc23.x * inv + bv0.z;
    float v3 = acc23.y * inv + bv0.w;
    float v4 = acc45.x * inv + bv1.x;
    float v5 = acc45.y * inv + bv1.y;
    float v6 = acc67.x * inv + bv1.z;
    float v7 = acc67.y * inv + bv1.w;
    v0 = v0 > 0.f ? v0 : __expf(v0) - 1.f;
    v1 = v1 > 0.f ? v1 : __expf(v1) - 1.f;
    v2 = v2 > 0.f ? v2 : __expf(v2) - 1.f;
    v3 = v3 > 0.f ? v3 : __expf(v3) - 1.f;
    v4 = v4 > 0.f ? v4 : __expf(v4) - 1.f;
    v5 = v5 > 0.f ? v5 : __expf(v5) - 1.f;
    v6 = v6 > 0.f ? v6 : __expf(v6) - 1.f;
    v7 = v7 > 0.f ? v7 : __expf(v7) - 1.f;
    if (hprev) {
        float4 h0 = ((const float4*)hprev)[d * 64 + q * 2];
        float4 h1 = ((const float4*)hprev)[d * 64 + q * 2 + 1];
        v0 += h0.x; v1 += h0.y; v2 += h0.z; v3 += h0.w;
        v4 += h1.x; v5 += h1.y; v6 += h1.z; v7 += h1.w;
    }
    if (half == 0) {
        if (hout) {
            ((float4*)hout)[d * 64 + q * 2]     = (float4){v0, v1, v2, v3};
            ((float4*)hout)[d * 64 + q * 2 + 1] = (float4){v4, v5, v6, v7};
        }
        uint4 pb;
        pb.x = (unsigned int)f2bf(v0) | ((unsigned int)f2bf(v1) << 16);
        pb.y = (unsigned int)f2bf(v2) | ((unsigned int)f2bf(v3) << 16);
        pb.z = (unsigned int)f2bf(v4) | ((unsigned int)f2bf(v5) << 16);
        pb.w = (unsigned int)f2bf(v6) | ((unsigned int)f2bf(v7) << 16);
        ((uint4*)houtb)[d * 32 + q] = pb;
    }
}

// ---------------- pooling (stage 1 reads bf16 h) ----------------
__global__ __launch_bounds__(256) void pool_partial_kernel(
        const ushortT* __restrict__ hb, float* __restrict__ psum, float* __restrict__ pmax) {
    int blk = blockIdx.x;
    int tid = threadIdx.x;
    int g = blk / POOL_CHUNKS;
    int ch = blk % POOL_CHUNKS;
    const ushortT* base = hb + ((size_t)g * NODES_PER_G + ch * NODES_PER_CHUNK) * HC;
    float sum = 0.f, mx = -INFINITY;
    for (int n = 0; n < NODES_PER_CHUNK; n++) {
        float v = __uint_as_float(((unsigned int)base[n * HC + tid]) << 16);
        sum += v;
        mx = fmaxf(mx, v);
    }
    psum[blk * HC + tid] = sum;
    pmax[blk * HC + tid] = mx;
}

__global__ __launch_bounds__(256) void pool_out_kernel(
        const float* __restrict__ psum, const float* __restrict__ pmax,
        const float* __restrict__ Wout, const float* __restrict__ bout,
        float* __restrict__ out) {
    int g = blockIdx.x;
    int tid = threadIdx.x;
    __shared__ float xg[2 * HC];
    float sum = 0.f, mx = -INFINITY;
    for (int c = 0; c < POOL_CHUNKS; c++) {
        sum += psum[(g * POOL_CHUNKS + c) * HC + tid];
        mx = fmaxf(mx, pmax[(g * POOL_CHUNKS + c) * HC + tid]);
    }
    xg[tid] = sum * (1.0f / NODES_PER_G);
    xg[HC + tid] = mx;
    __syncthreads();
    if (tid < OUT_DIM) {
        float acc = bout[tid];
        for (int j = 0; j < 2 * HC; j++) acc += xg[j] * Wout[j * OUT_DIM + tid];
        out[g * OUT_DIM + tid] = acc;
    }
}

// ---------------- launcher ----------------

extern "C" void kernel_launch(void* const* d_in, const int* in_sizes, int n_in,
                              void* d_out, int out_size, void* d_ws, size_t ws_size,
                              hipStream_t stream) {
    const float* x    = (const float*)d_in[0];
    const int*   ei   = (const int*)d_in[1];
    const float* Win  = (const float*)d_in[3];
    const float* bin  = (const float*)d_in[4];
    const float* Wout = (const float*)d_in[5];
    const float* bout = (const float*)d_in[6];
    const float* Wl[3] = {(const float*)d_in[7],  (const float*)d_in[11], (const float*)d_in[15]};
    const float* Wr[3] = {(const float*)d_in[8],  (const float*)d_in[12], (const float*)d_in[16]};
    const float* att[3] = {(const float*)d_in[9], (const float*)d_in[13], (const float*)d_in[17]};
    const float* bb[3] = {(const float*)d_in[10], (const float*)d_in[14], (const float*)d_in[18]};
    float* out = (float*)d_out;

    const int* esrc = ei;
    const int* edst = ei + N_EDGES;

    float* hA   = (float*)d_ws;
    float* hB   = hA + (size_t)N_NODES * HC;
    float* psum = hB + (size_t)N_NODES * HC;
    float* pmax = psum + (size_t)G_GRAPHS * POOL_CHUNKS * HC;
    ushortT* h0b = (ushortT*)(pmax + (size_t)G_GRAPHS * POOL_CHUNKS * HC);
    ushortT* hAb = h0b + (size_t)N_NODES * C_DIM;
    ushortT* hBb = hAb + (size_t)N_NODES * HC;
    ushortT* XLb = hBb + (size_t)N_NODES * HC;
    ushortT* XRb = XLb + (size_t)N_NODES * HC;
    ushortT* Bt0 = XRb + (size_t)N_NODES * HC;
    ushortT* Bt1 = Bt0 + 512 * 64;
    ushortT* Bt2 = Bt1 + 512 * 256;
    int* fill  = (int*)(Bt2 + 512 * 256);
    int* ell   = fill + N_NODES;                 // N_NODES * 64 ints

    (void)hipMemsetAsync(fill, 0, N_NODES * sizeof(int), stream);

    front_kernel<<<SCAT_NB + INPROJ_NB + 384, 256, 0, stream>>>(
        esrc, edst, fill, ell, x, Win, bin, h0b,
        Wl[0], Wr[0], Wl[1], Wr[1], Wl[2], Wr[2], Bt0, Bt1, Bt2);

    dim3 ggrid(512 / GBN, (N_NODES + GBM - 1) / GBM);

    gemm_mfma_kernel<<<ggrid, 256, 0, stream>>>(h0b, Bt0, XLb, XRb, N_NODES, C_DIM);
    gat_layer_kernel<<<GAT_NB, 256, 0, stream>>>(XLb, XRb, ell, fill, att[0], bb[0],
                                                 nullptr, hA, hAb);

    gemm_mfma_kernel<<<ggrid, 256, 0, stream>>>(hAb, Bt1, XLb, XRb, N_NODES, HC);
    gat_layer_kernel<<<GAT_NB, 256, 0, stream>>>(XLb, XRb, ell, fill, att[1], bb[1],
                                                 hA, hB, hBb);

    gemm_mfma_kernel<<<ggrid, 256, 0, stream>>>(hBb, Bt2, XLb, XRb, N_NODES, HC);
    gat_layer_kernel<<<GAT_NB, 256, 0, stream>>>(XLb, XRb, ell, fill, att[2], bb[2],
                                                 hB, nullptr, hAb);

    pool_partial_kernel<<<G_GRAPHS * POOL_CHUNKS, 256, 0, stream>>>(hAb, psum, pmax);
    pool_out_kernel<<<G_GRAPHS, 256, 0, stream>>>(psum, pmax, Wout, bout, out);
}